// Round 7
// baseline (1947.614 us; speedup 1.0000x reference)
//
#include <hip/hip_runtime.h>

// ---------------- constants ----------------
#define BATCH 4
#define NPIL 12000
#define NPTS 32
#define NCH 9
#define NXg 432
#define NYg 496
#define OHh 248
#define OWw 216
#define HWp (OHh*OWw)          // 53568

__device__ __forceinline__ float b2f(unsigned int u) {
    union { unsigned int i; float f; } x; x.i = (u & 0xffffu) << 16; return x.f;
}
__device__ __forceinline__ unsigned short f2b(float f) {
    union { float f; unsigned int i; } x; x.f = f;
    unsigned int r = x.i + 0x7fffu + ((x.i >> 16) & 1u);   // RNE
    return (unsigned short)(r >> 16);
}
__device__ __forceinline__ float ldin(const void* p, int i, int isbf) {
    return isbf ? b2f(((const unsigned short*)p)[i]) : ((const float*)p)[i];
}

template<typename ST> struct SIO;
template<> struct SIO<float> {
    static __device__ __forceinline__ float4 ld4(const float* p){ return *(const float4*)p; }
};
template<> struct SIO<unsigned short> {
    static __device__ __forceinline__ float4 ld4(const unsigned short* p){
        uint2 d = *(const uint2*)p;
        return make_float4(b2f(d.x), b2f(d.x >> 16), b2f(d.y), b2f(d.y >> 16));
    }
};

// fp32 sentinel (visible now that output is fp32)
__global__ void sentinel_kernel(float* out, float val) {
    if (threadIdx.x == 0) out[0] = val;
}

// ---------------- per-tensor dtype detector (fp32 vs bf16, robustness) ----------------
__device__ __forceinline__ int plaus16(unsigned short h) {
    if ((h & 0x7fffu) == 0) return 1;
    unsigned e = (h >> 7) & 0xffu;
    return (e >= 106 && e <= 132) ? 1 : 0;
}

__global__ __launch_bounds__(1024) void detect_all(
    const void* q0,  const void* q1,  const void* q2,  const void* q3,
    const void* q4,  const void* q5,  const void* q6,  const void* q7,
    const void* q8,  const void* q9,  const void* q10, const void* q11,
    const void* q12, const void* q13, const void* q14, const void* q15,
    const void* q16, const void* q17, const void* q18, const void* q19,
    const void* q20, const void* q21, int* __restrict__ flags)
{
    __shared__ int votes[22];
    const void* ptrs[22] = {q0,q1,q2,q3,q4,q5,q6,q7,q8,q9,q10,q11,
                            q12,q13,q14,q15,q16,q17,q18,q19,q20,q21};
    const int Ks[22]   = {64,64,32,32,32,32,64,32,32,32,32,64,64,64,64,64,64,3,64,7,64,2};
    const int didx[22] = {0,3,4,5,6,7,8,9,10,11,12,13,14,15,16,17,18,19,20,21,22,23};
    const int tid = threadIdx.x;
    if (tid < 22) votes[tid] = 0;
    __syncthreads();
    int off = 0;
    #pragma unroll 1
    for (int t = 0; t < 22; ++t) {
        const int K = Ks[t];
        if (tid >= off && tid < off + K) {
            unsigned w = ((const unsigned*)ptrs[t])[tid - off];
            if (plaus16((unsigned short)w) && plaus16((unsigned short)(w >> 16)))
                atomicAdd(&votes[t], 1);
        }
        off += K;
    }
    __syncthreads();
    if (tid < 22) {
        int isbf;
        if (tid == 17 || tid == 19 || tid == 21) {      // tiny biases pooled
            int pv = votes[17] + votes[19] + votes[21];
            isbf = (pv * 4 >= 3 * 12);
        } else {
            isbf = (votes[tid] * 4 >= 3 * Ks[tid]);
        }
        flags[didx[tid]] = isbf;
    }
}

// ---------------- weight transpose: OIHW -> [ky][kx][ic][oc] fp32 ----------------
__global__ __launch_bounds__(256) void prep_weights(
    const void* __restrict__ w1, const void* __restrict__ w2,
    float* __restrict__ wt1, float* __restrict__ wt2,
    const int* __restrict__ flags)
{
    const int f1 = flags[8], f2 = flags[13];
    int i = blockIdx.x * 256 + threadIdx.x;
    if (i < 64*64*9) {
        int kx = i % 3; int t = i / 3; int ky = t % 3; t /= 3; int ic = t % 64; int oc = t / 64;
        wt1[((ky*3 + kx)*64 + ic)*64 + oc] = ldin(w1, i, f1);
    }
    if (i < 128*64*9) {
        int kx = i % 3; int t = i / 3; int ky = t % 3; t /= 3; int ic = t % 64; int oc = t / 64;
        wt2[((ky*3 + kx)*64 + ic)*128 + oc] = ldin(w2, i, f2);
    }
}

// ---------------- PFN + scatter (one batch), canvas NHWC bf16 [NY,NX,64] ----------------
__global__ __launch_bounds__(256) void pfn_scatter(
    const void* __restrict__ pillars, const int* __restrict__ coords,
    const void* __restrict__ pfn_w,
    const void* __restrict__ g, const void* __restrict__ bb,
    const void* __restrict__ m, const void* __restrict__ v,
    const int* __restrict__ flags, int batch,
    unsigned short* __restrict__ canvas)
{
    __shared__ float lds[4][NPTS*NCH];
    const int wslot = threadIdx.x >> 6;
    const int lane  = threadIdx.x & 63;
    const int p = blockIdx.x * 4 + wslot;
    const size_t pg = (size_t)batch * NPIL + p;

    if (flags[0]) {
        const unsigned short* src = (const unsigned short*)pillars + pg * (NPTS*NCH);
        for (int idx = lane; idx < NPTS*NCH; idx += 64) lds[wslot][idx] = b2f(src[idx]);
    } else {
        const float4* src = (const float4*)((const float*)pillars + pg * (NPTS*NCH));
        for (int idx = lane; idx < (NPTS*NCH)/4; idx += 64)
            *(float4*)&lds[wslot][idx*4] = src[idx];
    }
    float w[NCH];
    const int fW = flags[3];
    #pragma unroll
    for (int c = 0; c < NCH; ++c) w[c] = ldin(pfn_w, lane*NCH + c, fW);
    float s = ldin(g, lane, flags[4]) / sqrtf(ldin(v, lane, flags[7]) + 1e-5f);
    float t = ldin(bb, lane, flags[5]) - ldin(m, lane, flags[6]) * s;
    __syncthreads();

    float mx = 0.0f;                   // relu >= 0 -> 0 is a safe identity
    #pragma unroll 4
    for (int n = 0; n < NPTS; ++n) {
        const float* r = &lds[wslot][n*NCH];
        float acc = r[0] * w[0];
        #pragma unroll
        for (int c = 1; c < NCH; ++c) acc = fmaf(r[c], w[c], acc);
        mx = fmaxf(mx, fmaxf(fmaf(acc, s, t), 0.0f));
    }
    const int cx = coords[pg*2], cy = coords[pg*2 + 1];
    if (cx + cy != 0 && cx >= 0 && cx < NXg && cy >= 0 && cy < NYg)
        canvas[((size_t)cy*NXg + cx)*64 + lane] = f2b(mx);
}

// ---------------- 3x3 conv + BN + ReLU, NHWC, IC=64, one batch ----------------
template<typename STI, int OC, int STRIDE, int TILE, int IXW, int PX, int NPX>
__global__ __launch_bounds__(256) void conv3x3(
    const STI* __restrict__ in, int IH, int IW,
    const float* __restrict__ wt,
    const void* __restrict__ g, const void* __restrict__ bb,
    const void* __restrict__ m, const void* __restrict__ v,
    const int* __restrict__ flags, int fbase,
    float* __restrict__ out, int OH, int OW)
{
    __shared__ __align__(16) float lin[IXW*64];
    __shared__ __align__(16) float lw[64*OC];
    const int tid = threadIdx.x;
    const int oc = tid % OC;
    const int pgr = tid / OC;
    const int oy = blockIdx.y, ox0 = blockIdx.x * TILE;
    const int x0 = ox0*STRIDE - 1;

    float acc[NPX];
    #pragma unroll
    for (int i = 0; i < NPX; ++i) acc[i] = 0.0f;

    #pragma unroll 1
    for (int ky = 0; ky < 3; ++ky) {
        const int iy = oy*STRIDE + ky - 1;
        if (iy < 0 || iy >= IH) continue;           // block-uniform
        __syncthreads();
        {
            const STI* row = in + (size_t)iy*IW*64;
            for (int idx = tid; idx < IXW*16; idx += 256) {
                int px = idx >> 4, grp = idx & 15;
                int gx = x0 + px;
                float4 vv = make_float4(0.f, 0.f, 0.f, 0.f);
                if (gx >= 0 && gx < IW)
                    vv = SIO<STI>::ld4(&row[(size_t)gx*64 + grp*4]);
                *(float4*)&lin[px*64 + grp*4] = vv;
            }
        }
        #pragma unroll 1
        for (int kx = 0; kx < 3; ++kx) {
            __syncthreads();
            {
                const float4* src = (const float4*)(wt + ((size_t)(ky*3 + kx))*64*OC);
                float4* dst = (float4*)lw;
                for (int idx = tid; idx < 64*OC/4; idx += 256) dst[idx] = src[idx];
            }
            __syncthreads();
            #pragma unroll
            for (int icg = 0; icg < 16; ++icg) {
                const float w0  = lw[(icg*4 + 0)*OC + oc];
                const float w1_ = lw[(icg*4 + 1)*OC + oc];
                const float w2_ = lw[(icg*4 + 2)*OC + oc];
                const float w3_ = lw[(icg*4 + 3)*OC + oc];
                #pragma unroll
                for (int i = 0; i < NPX; ++i) {
                    const int lx = (pgr + PX*i)*STRIDE + kx;
                    const float4 vv = *(const float4*)&lin[lx*64 + icg*4];
                    acc[i] = fmaf(vv.x, w0, acc[i]);
                    acc[i] = fmaf(vv.y, w1_, acc[i]);
                    acc[i] = fmaf(vv.z, w2_, acc[i]);
                    acc[i] = fmaf(vv.w, w3_, acc[i]);
                }
            }
        }
    }
    const float s = ldin(g, oc, flags[fbase]) / sqrtf(ldin(v, oc, flags[fbase+3]) + 1e-5f);
    const float t = ldin(bb, oc, flags[fbase+1]) - ldin(m, oc, flags[fbase+2]) * s;
    #pragma unroll
    for (int i = 0; i < NPX; ++i) {
        const int ox = ox0 + pgr + PX*i;
        out[((size_t)oy*OW + ox)*OC + oc] = fmaxf(fmaf(acc[i], s, t), 0.0f);
    }
}

// ---------------- detection heads (1x1 convs), one batch, FP32 OUTPUT ----------------
__global__ __launch_bounds__(256) void heads_kernel(
    const float* __restrict__ x2,
    const void* __restrict__ cls_w, const void* __restrict__ cls_b,
    const void* __restrict__ reg_w, const void* __restrict__ reg_b,
    const void* __restrict__ dir_w, const void* __restrict__ dir_b,
    const int* __restrict__ flags, int batch,
    float* __restrict__ out)
{
    __shared__ float lw[24*128];
    __shared__ float lb[24];
    const int tid = threadIdx.x;
    for (int idx = tid; idx < 6*128;  idx += 256) lw[idx]          = ldin(cls_w, idx, flags[18]);
    for (int idx = tid; idx < 14*128; idx += 256) lw[6*128 + idx]  = ldin(reg_w, idx, flags[20]);
    for (int idx = tid; idx < 4*128;  idx += 256) lw[20*128 + idx] = ldin(dir_w, idx, flags[22]);
    if (tid < 6)       lb[tid] = ldin(cls_b, tid, flags[19]);
    else if (tid < 20) lb[tid] = ldin(reg_b, tid - 6, flags[21]);
    else if (tid < 24) lb[tid] = ldin(dir_b, tid - 20, flags[23]);
    __syncthreads();

    const int pix = blockIdx.x * 256 + tid;
    if (pix >= HWp) return;
    const float* xrow = x2 + (size_t)pix * 128;

    float acc[24];
    #pragma unroll
    for (int o = 0; o < 24; ++o) acc[o] = lb[o];
    #pragma unroll 2
    for (int kb = 0; kb < 128; kb += 16) {
        float xv[16];
        #pragma unroll
        for (int j = 0; j < 4; ++j) {
            float4 v4 = *(const float4*)(xrow + kb + 4*j);
            xv[4*j] = v4.x; xv[4*j+1] = v4.y; xv[4*j+2] = v4.z; xv[4*j+3] = v4.w;
        }
        #pragma unroll
        for (int k = 0; k < 16; ++k)
            #pragma unroll
            for (int o = 0; o < 24; ++o)
                acc[o] = fmaf(xv[k], lw[o*128 + kb + k], acc[o]);
    }
    const size_t reg_base = (size_t)BATCH*6*HWp;
    const size_t dir_base = reg_base + (size_t)BATCH*14*HWp;
    #pragma unroll
    for (int o = 0; o < 6; ++o)
        out[((size_t)batch*6 + o)*HWp + pix] = acc[o];
    #pragma unroll
    for (int o = 0; o < 14; ++o)
        out[reg_base + ((size_t)batch*14 + o)*HWp + pix] = acc[6 + o];
    #pragma unroll
    for (int o = 0; o < 4; ++o)
        out[dir_base + ((size_t)batch*4 + o)*HWp + pix] = acc[20 + o];
}

extern "C" void kernel_launch(void* const* d_in, const int* in_sizes, int n_in,
                              void* d_out, int out_size, void* d_ws, size_t ws_size,
                              hipStream_t stream) {
    static const int EXPECT[24] = {13824000,96000,48000,576,64,64,64,64,36864,
                                   64,64,64,64,73728,128,128,128,128,768,6,1792,14,512,4};
    const void* din[24];
    {
        bool used[24] = {false};
        int perm[24];
        bool ok = (n_in >= 24);
        if (ok) {
            for (int j = 0; j < 24 && ok; ++j) {
                perm[j] = -1;
                for (int i = 0; i < 24; ++i)
                    if (!used[i] && in_sizes[i] == EXPECT[j]) { perm[j] = i; used[i] = true; break; }
                if (perm[j] < 0) ok = false;
            }
        }
        for (int j = 0; j < 24; ++j) din[j] = d_in[ok ? perm[j] : j];
        if (!ok) {
            sentinel_kernel<<<1, 64, 0, stream>>>((float*)d_out, 13000.0f + n_in);
            return;
        }
    }
    const int* coords = (const int*)din[1];
    float* out = (float*)d_out;

    // workspace: flags 256B | wt1 147KB | wt2 295KB | x1 13.7MB | canvas 27.4MB (x2 aliases)
    const size_t NEED = 41582848ull;
    if (ws_size < NEED) {
        sentinel_kernel<<<1, 64, 0, stream>>>(out, 10000.0f + (float)(ws_size >> 20));
        return;
    }
    char* ws = (char*)d_ws;
    int*   flags = (int*)ws;
    float* wt1   = (float*)(ws + 256);
    float* wt2   = (float*)(ws + 147712);
    float* x1    = (float*)(ws + 442624);                       // [248,216,64] f32
    unsigned short* canvas = (unsigned short*)(ws + 14156032);  // [496,432,64] bf16
    float* x2    = (float*)(ws + 14156032);                     // [248,216,128] f32, aliases canvas

    detect_all<<<1, 1024, 0, stream>>>(
        din[0], din[3], din[4], din[5], din[6], din[7],
        din[8], din[9], din[10], din[11], din[12],
        din[13], din[14], din[15], din[16], din[17],
        din[18], din[19], din[20], din[21], din[22], din[23], flags);
    prep_weights<<<288, 256, 0, stream>>>(din[8], din[13], wt1, wt2, flags);

    for (int b = 0; b < BATCH; ++b) {
        hipMemsetAsync(canvas, 0, (size_t)NYg*NXg*64*2, stream);
        pfn_scatter<<<NPIL/4, 256, 0, stream>>>(
            din[0], coords, din[3], din[4], din[5], din[6], din[7], flags, b, canvas);
        // conv1: 64ch 496x432 -> 64ch 248x216, stride 2 (LDS ~22.8 KB)
        conv3x3<unsigned short, 64, 2, 12, 25, 4, 3><<<dim3(OWw/12, OHh), 256, 0, stream>>>(
            canvas, NYg, NXg, wt1, din[9], din[10], din[11], din[12], flags, 9, x1, OHh, OWw);
        // conv2: 64ch 248x216 -> 128ch 248x216, stride 1 (LDS ~39.4 KB); x2 overwrites canvas
        conv3x3<float, 128, 1, 24, 26, 2, 12><<<dim3(OWw/24, OHh), 256, 0, stream>>>(
            x1, OHh, OWw, wt2, din[14], din[15], din[16], din[17], flags, 14, x2, OHh, OWw);
        heads_kernel<<<(HWp + 255)/256, 256, 0, stream>>>(
            x2, din[18], din[19], din[20], din[21], din[22], din[23], flags, b, out);
    }
}

// Round 8
// 1043.459 us; speedup vs baseline: 1.8665x; 1.8665x over previous
//
#include <hip/hip_runtime.h>

// ---------------- constants ----------------
#define BATCH 4
#define NPIL 12000
#define NPTS 32
#define NCH 9
#define NXg 432
#define NYg 496
#define OHh 248
#define OWw 216
#define HWp (OHh*OWw)          // 53568

__device__ __forceinline__ float b2f(unsigned int u) {
    union { unsigned int i; float f; } x; x.i = (u & 0xffffu) << 16; return x.f;
}
__device__ __forceinline__ unsigned short f2b(float f) {
    union { float f; unsigned int i; } x; x.f = f;
    unsigned int r = x.i + 0x7fffu + ((x.i >> 16) & 1u);   // RNE
    return (unsigned short)(r >> 16);
}
__device__ __forceinline__ float ldin(const void* p, int i, int isbf) {
    return isbf ? b2f(((const unsigned short*)p)[i]) : ((const float*)p)[i];
}

__global__ void sentinel_kernel(float* out, float val) {
    if (threadIdx.x == 0) out[0] = val;
}

// ---------------- per-tensor dtype detector (robustness; all fp32 in practice) ----------------
__device__ __forceinline__ int plaus16(unsigned short h) {
    if ((h & 0x7fffu) == 0) return 1;
    unsigned e = (h >> 7) & 0xffu;
    return (e >= 106 && e <= 132) ? 1 : 0;
}

__global__ __launch_bounds__(1024) void detect_all(
    const void* q0,  const void* q1,  const void* q2,  const void* q3,
    const void* q4,  const void* q5,  const void* q6,  const void* q7,
    const void* q8,  const void* q9,  const void* q10, const void* q11,
    const void* q12, const void* q13, const void* q14, const void* q15,
    const void* q16, const void* q17, const void* q18, const void* q19,
    const void* q20, const void* q21, int* __restrict__ flags)
{
    __shared__ int votes[22];
    const void* ptrs[22] = {q0,q1,q2,q3,q4,q5,q6,q7,q8,q9,q10,q11,
                            q12,q13,q14,q15,q16,q17,q18,q19,q20,q21};
    const int Ks[22]   = {64,64,32,32,32,32,64,32,32,32,32,64,64,64,64,64,64,3,64,7,64,2};
    const int didx[22] = {0,3,4,5,6,7,8,9,10,11,12,13,14,15,16,17,18,19,20,21,22,23};
    const int tid = threadIdx.x;
    if (tid < 22) votes[tid] = 0;
    __syncthreads();
    int off = 0;
    #pragma unroll 1
    for (int t = 0; t < 22; ++t) {
        const int K = Ks[t];
        if (tid >= off && tid < off + K) {
            unsigned w = ((const unsigned*)ptrs[t])[tid - off];
            if (plaus16((unsigned short)w) && plaus16((unsigned short)(w >> 16)))
                atomicAdd(&votes[t], 1);
        }
        off += K;
    }
    __syncthreads();
    if (tid < 22) {
        int isbf;
        if (tid == 17 || tid == 19 || tid == 21) {
            int pv = votes[17] + votes[19] + votes[21];
            isbf = (pv * 4 >= 3 * 12);
        } else {
            isbf = (votes[tid] * 4 >= 3 * Ks[tid]);
        }
        flags[didx[tid]] = isbf;
    }
}

// ---------------- weight transpose: OIHW -> [ky*3+kx][ic][oc] fp32 ----------------
__global__ __launch_bounds__(256) void prep_weights(
    const void* __restrict__ w1, const void* __restrict__ w2,
    float* __restrict__ wt1, float* __restrict__ wt2,
    const int* __restrict__ flags)
{
    const int f1 = flags[8], f2 = flags[13];
    int i = blockIdx.x * 256 + threadIdx.x;
    if (i < 64*64*9) {
        int kx = i % 3; int t = i / 3; int ky = t % 3; t /= 3; int ic = t % 64; int oc = t / 64;
        wt1[((ky*3 + kx)*64 + ic)*64 + oc] = ldin(w1, i, f1);
    }
    if (i < 128*64*9) {
        int kx = i % 3; int t = i / 3; int ky = t % 3; t /= 3; int ic = t % 64; int oc = t / 64;
        wt2[((ky*3 + kx)*64 + ic)*128 + oc] = ldin(w2, i, f2);
    }
}

// ---------------- PFN + scatter (one batch), canvas NHWC bf16 [NY,NX,64] ----------------
__global__ __launch_bounds__(256) void pfn_scatter(
    const void* __restrict__ pillars, const int* __restrict__ coords,
    const void* __restrict__ pfn_w,
    const void* __restrict__ g, const void* __restrict__ bb,
    const void* __restrict__ m, const void* __restrict__ v,
    const int* __restrict__ flags, int batch,
    unsigned short* __restrict__ canvas)
{
    __shared__ float lds[4][NPTS*NCH];
    const int wslot = threadIdx.x >> 6;
    const int lane  = threadIdx.x & 63;
    const int p = blockIdx.x * 4 + wslot;
    const size_t pg = (size_t)batch * NPIL + p;

    if (flags[0]) {
        const unsigned short* src = (const unsigned short*)pillars + pg * (NPTS*NCH);
        for (int idx = lane; idx < NPTS*NCH; idx += 64) lds[wslot][idx] = b2f(src[idx]);
    } else {
        const float4* src = (const float4*)((const float*)pillars + pg * (NPTS*NCH));
        for (int idx = lane; idx < (NPTS*NCH)/4; idx += 64)
            *(float4*)&lds[wslot][idx*4] = src[idx];
    }
    float w[NCH];
    const int fW = flags[3];
    #pragma unroll
    for (int c = 0; c < NCH; ++c) w[c] = ldin(pfn_w, lane*NCH + c, fW);
    float s = ldin(g, lane, flags[4]) / sqrtf(ldin(v, lane, flags[7]) + 1e-5f);
    float t = ldin(bb, lane, flags[5]) - ldin(m, lane, flags[6]) * s;
    __syncthreads();

    float mx = 0.0f;
    #pragma unroll 4
    for (int n = 0; n < NPTS; ++n) {
        const float* r = &lds[wslot][n*NCH];
        float acc = r[0] * w[0];
        #pragma unroll
        for (int c = 1; c < NCH; ++c) acc = fmaf(r[c], w[c], acc);
        mx = fmaxf(mx, fmaxf(fmaf(acc, s, t), 0.0f));
    }
    const int cx = coords[pg*2], cy = coords[pg*2 + 1];
    if (cx + cy != 0 && cx >= 0 && cx < NXg && cy >= 0 && cy < NYg)
        canvas[((size_t)cy*NXg + cx)*64 + lane] = f2b(mx);
}

// ---------------- conv1: canvas bf16 [496,432,64] -> x1 fp32 [248,216,64] ----------------
// stride 2. 256 thr = 16 oc-threads (4 oc each) x 16 px-threads (7 contiguous px).
// per-ky staging: lw[3kx][64ic][64oc] fp32 (49.2 KB) + lin bf16 225x64 (28.8 KB).
__global__ __launch_bounds__(256, 2) void conv1_mt(
    const unsigned short* __restrict__ canvas,
    const float* __restrict__ wt,          // [ky*3+kx][ic][64]
    const void* __restrict__ g, const void* __restrict__ bb,
    const void* __restrict__ m, const void* __restrict__ v,
    const int* __restrict__ flags,
    float* __restrict__ out)
{
    __shared__ __align__(16) unsigned short lin[225*64];
    __shared__ __align__(16) float lw[3*64*64];
    const int tid = threadIdx.x;
    const int oc_t = tid & 15, pg = tid >> 4;
    const int oc0 = oc_t*4;
    const int bx = blockIdx.x, oy = blockIdx.y;
    const int gx0 = bx*224 - 1;            // input x of lin[0]

    float4 acc[7];
    #pragma unroll
    for (int i = 0; i < 7; ++i) acc[i] = make_float4(0.f,0.f,0.f,0.f);

    #pragma unroll 1
    for (int ky = 0; ky < 3; ++ky) {
        const int iy = 2*oy + ky - 1;
        __syncthreads();
        if (iy < 0 || iy >= NYg) continue;     // block-uniform
        {   // stage weights for all 3 kx: 12288 floats = 3072 float4
            const float4* src = (const float4*)(wt + (size_t)ky*3*64*64);
            float4* dst = (float4*)lw;
            for (int q = tid; q < 3*64*16; q += 256) dst[q] = src[q];
        }
        {   // stage input row, bf16, zero-padded: 225*16 uint2-quads
            const unsigned short* row = canvas + (size_t)iy*NXg*64;
            for (int q = tid; q < 225*16; q += 256) {
                int px = q >> 4, ic4 = (q & 15) << 2;
                int gx = gx0 + px;
                uint2 d = make_uint2(0u, 0u);
                if (gx >= 0 && gx < NXg) d = *(const uint2*)&row[(size_t)gx*64 + ic4];
                *(uint2*)&lin[px*64 + ic4] = d;
            }
        }
        __syncthreads();
        #pragma unroll 1
        for (int icg = 0; icg < 16; ++icg) {
            float4 q[15];                      // lx = 2*(pg*7+i)+kx -> local j = 14*pg + 2i + kx
            #pragma unroll
            for (int j = 0; j < 15; ++j) {
                uint2 d = *(const uint2*)&lin[(14*pg + j)*64 + icg*4];
                q[j] = make_float4(b2f(d.x), b2f(d.x >> 16), b2f(d.y), b2f(d.y >> 16));
            }
            #pragma unroll
            for (int kx = 0; kx < 3; ++kx)
            #pragma unroll
            for (int ic = 0; ic < 4; ++ic) {
                const float4 w4 = *(const float4*)&lw[(kx*64 + icg*4 + ic)*64 + oc0];
                #pragma unroll
                for (int i = 0; i < 7; ++i) {
                    const float a = ((const float*)&q[2*i + kx])[ic];
                    acc[i].x = fmaf(a, w4.x, acc[i].x);
                    acc[i].y = fmaf(a, w4.y, acc[i].y);
                    acc[i].z = fmaf(a, w4.z, acc[i].z);
                    acc[i].w = fmaf(a, w4.w, acc[i].w);
                }
            }
        }
    }
    float s[4], t[4];
    #pragma unroll
    for (int c = 0; c < 4; ++c) {
        s[c] = ldin(g, oc0+c, flags[9]) / sqrtf(ldin(v, oc0+c, flags[12]) + 1e-5f);
        t[c] = ldin(bb, oc0+c, flags[10]) - ldin(m, oc0+c, flags[11]) * s[c];
    }
    #pragma unroll
    for (int i = 0; i < 7; ++i) {
        const int px = bx*112 + pg*7 + i;
        if (px < OWw) {
            float4 r;
            r.x = fmaxf(fmaf(acc[i].x, s[0], t[0]), 0.f);
            r.y = fmaxf(fmaf(acc[i].y, s[1], t[1]), 0.f);
            r.z = fmaxf(fmaf(acc[i].z, s[2], t[2]), 0.f);
            r.w = fmaxf(fmaf(acc[i].w, s[3], t[3]), 0.f);
            *(float4*)&out[((size_t)oy*OWw + px)*64 + oc0] = r;
        }
    }
}

// ---------------- conv2: x1 fp32 [248,216,64] -> x2 fp32 [248,216,128] ----------------
// stride 1. grid.z splits OC in halves of 64. Same thread blocking as conv1.
// per-ky staging: lw[3kx][64ic][64oc-slice] (49.2 KB) + lin fp32 114x64 (29.2 KB).
__global__ __launch_bounds__(256, 2) void conv2_mt(
    const float* __restrict__ x1,
    const float* __restrict__ wt,          // [ky*3+kx][ic][128]
    const void* __restrict__ g, const void* __restrict__ bb,
    const void* __restrict__ m, const void* __restrict__ v,
    const int* __restrict__ flags,
    float* __restrict__ out)
{
    __shared__ __align__(16) float lin[114*64];
    __shared__ __align__(16) float lw[3*64*64];
    const int tid = threadIdx.x;
    const int oc_t = tid & 15, pg = tid >> 4;
    const int z = blockIdx.z;
    const int oc = z*64 + oc_t*4;
    const int bx = blockIdx.x, oy = blockIdx.y;
    const int gx0 = bx*112 - 1;

    float4 acc[7];
    #pragma unroll
    for (int i = 0; i < 7; ++i) acc[i] = make_float4(0.f,0.f,0.f,0.f);

    #pragma unroll 1
    for (int ky = 0; ky < 3; ++ky) {
        const int iy = oy + ky - 1;
        __syncthreads();
        if (iy < 0 || iy >= OHh) continue;     // block-uniform
        {   // stage weights, oc-slice z: [kx][ic][64]
            for (int j = tid; j < 3*64*16; j += 256) {
                int kx = j >> 10, r = j & 1023, ic = r >> 4, qo = r & 15;
                *(float4*)&lw[(kx*64 + ic)*64 + qo*4] =
                    *(const float4*)&wt[(((size_t)(ky*3 + kx))*64 + ic)*128 + z*64 + qo*4];
            }
        }
        {   // stage input row, fp32, zero-padded: 114*16 quads
            const float* row = x1 + (size_t)iy*OWw*64;
            for (int q = tid; q < 114*16; q += 256) {
                int px = q >> 4, ic4 = (q & 15) << 2;
                int gx = gx0 + px;
                float4 d = make_float4(0.f,0.f,0.f,0.f);
                if (gx >= 0 && gx < OWw) d = *(const float4*)&row[(size_t)gx*64 + ic4];
                *(float4*)&lin[px*64 + ic4] = d;
            }
        }
        __syncthreads();
        #pragma unroll 1
        for (int icg = 0; icg < 16; ++icg) {
            float4 q[9];                       // local j = pg*7 + i + kx
            #pragma unroll
            for (int j = 0; j < 9; ++j)
                q[j] = *(const float4*)&lin[(pg*7 + j)*64 + icg*4];
            #pragma unroll
            for (int kx = 0; kx < 3; ++kx)
            #pragma unroll
            for (int ic = 0; ic < 4; ++ic) {
                const float4 w4 = *(const float4*)&lw[(kx*64 + icg*4 + ic)*64 + oc_t*4];
                #pragma unroll
                for (int i = 0; i < 7; ++i) {
                    const float a = ((const float*)&q[i + kx])[ic];
                    acc[i].x = fmaf(a, w4.x, acc[i].x);
                    acc[i].y = fmaf(a, w4.y, acc[i].y);
                    acc[i].z = fmaf(a, w4.z, acc[i].z);
                    acc[i].w = fmaf(a, w4.w, acc[i].w);
                }
            }
        }
    }
    float s[4], t[4];
    #pragma unroll
    for (int c = 0; c < 4; ++c) {
        s[c] = ldin(g, oc+c, flags[14]) / sqrtf(ldin(v, oc+c, flags[17]) + 1e-5f);
        t[c] = ldin(bb, oc+c, flags[15]) - ldin(m, oc+c, flags[16]) * s[c];
    }
    #pragma unroll
    for (int i = 0; i < 7; ++i) {
        const int px = bx*112 + pg*7 + i;
        if (px < OWw) {
            float4 r;
            r.x = fmaxf(fmaf(acc[i].x, s[0], t[0]), 0.f);
            r.y = fmaxf(fmaf(acc[i].y, s[1], t[1]), 0.f);
            r.z = fmaxf(fmaf(acc[i].z, s[2], t[2]), 0.f);
            r.w = fmaxf(fmaf(acc[i].w, s[3], t[3]), 0.f);
            *(float4*)&out[((size_t)oy*OWw + px)*128 + oc] = r;
        }
    }
}

// ---------------- detection heads (1x1 convs), one batch, fp32 out ----------------
__global__ __launch_bounds__(256) void heads_kernel(
    const float* __restrict__ x2,
    const void* __restrict__ cls_w, const void* __restrict__ cls_b,
    const void* __restrict__ reg_w, const void* __restrict__ reg_b,
    const void* __restrict__ dir_w, const void* __restrict__ dir_b,
    const int* __restrict__ flags, int batch,
    float* __restrict__ out)
{
    __shared__ float lw[24*128];
    __shared__ float lb[24];
    const int tid = threadIdx.x;
    for (int idx = tid; idx < 6*128;  idx += 256) lw[idx]          = ldin(cls_w, idx, flags[18]);
    for (int idx = tid; idx < 14*128; idx += 256) lw[6*128 + idx]  = ldin(reg_w, idx, flags[20]);
    for (int idx = tid; idx < 4*128;  idx += 256) lw[20*128 + idx] = ldin(dir_w, idx, flags[22]);
    if (tid < 6)       lb[tid] = ldin(cls_b, tid, flags[19]);
    else if (tid < 20) lb[tid] = ldin(reg_b, tid - 6, flags[21]);
    else if (tid < 24) lb[tid] = ldin(dir_b, tid - 20, flags[23]);
    __syncthreads();

    const int pix = blockIdx.x * 256 + tid;
    if (pix >= HWp) return;
    const float* xrow = x2 + (size_t)pix * 128;

    float acc[24];
    #pragma unroll
    for (int o = 0; o < 24; ++o) acc[o] = lb[o];
    #pragma unroll 2
    for (int kb = 0; kb < 128; kb += 16) {
        float xv[16];
        #pragma unroll
        for (int j = 0; j < 4; ++j) {
            float4 v4 = *(const float4*)(xrow + kb + 4*j);
            xv[4*j] = v4.x; xv[4*j+1] = v4.y; xv[4*j+2] = v4.z; xv[4*j+3] = v4.w;
        }
        #pragma unroll
        for (int k = 0; k < 16; ++k)
            #pragma unroll
            for (int o = 0; o < 24; ++o)
                acc[o] = fmaf(xv[k], lw[o*128 + kb + k], acc[o]);
    }
    const size_t reg_base = (size_t)BATCH*6*HWp;
    const size_t dir_base = reg_base + (size_t)BATCH*14*HWp;
    #pragma unroll
    for (int o = 0; o < 6; ++o)
        out[((size_t)batch*6 + o)*HWp + pix] = acc[o];
    #pragma unroll
    for (int o = 0; o < 14; ++o)
        out[reg_base + ((size_t)batch*14 + o)*HWp + pix] = acc[6 + o];
    #pragma unroll
    for (int o = 0; o < 4; ++o)
        out[dir_base + ((size_t)batch*4 + o)*HWp + pix] = acc[20 + o];
}

extern "C" void kernel_launch(void* const* d_in, const int* in_sizes, int n_in,
                              void* d_out, int out_size, void* d_ws, size_t ws_size,
                              hipStream_t stream) {
    static const int EXPECT[24] = {13824000,96000,48000,576,64,64,64,64,36864,
                                   64,64,64,64,73728,128,128,128,128,768,6,1792,14,512,4};
    const void* din[24];
    {
        bool used[24] = {false};
        int perm[24];
        bool ok = (n_in >= 24);
        if (ok) {
            for (int j = 0; j < 24 && ok; ++j) {
                perm[j] = -1;
                for (int i = 0; i < 24; ++i)
                    if (!used[i] && in_sizes[i] == EXPECT[j]) { perm[j] = i; used[i] = true; break; }
                if (perm[j] < 0) ok = false;
            }
        }
        for (int j = 0; j < 24; ++j) din[j] = d_in[ok ? perm[j] : j];
        if (!ok) {
            sentinel_kernel<<<1, 64, 0, stream>>>((float*)d_out, 13000.0f + n_in);
            return;
        }
    }
    const int* coords = (const int*)din[1];
    float* out = (float*)d_out;

    // workspace: flags 256B | wt1 147KB | wt2 295KB | x1 13.7MB | canvas 27.4MB (x2 aliases)
    const size_t NEED = 41582848ull;
    if (ws_size < NEED) {
        sentinel_kernel<<<1, 64, 0, stream>>>(out, 10000.0f + (float)(ws_size >> 20));
        return;
    }
    char* ws = (char*)d_ws;
    int*   flags = (int*)ws;
    float* wt1   = (float*)(ws + 256);
    float* wt2   = (float*)(ws + 147712);
    float* x1    = (float*)(ws + 442624);                       // [248,216,64] f32
    unsigned short* canvas = (unsigned short*)(ws + 14156032);  // [496,432,64] bf16
    float* x2    = (float*)(ws + 14156032);                     // [248,216,128] f32, aliases canvas

    detect_all<<<1, 1024, 0, stream>>>(
        din[0], din[3], din[4], din[5], din[6], din[7],
        din[8], din[9], din[10], din[11], din[12],
        din[13], din[14], din[15], din[16], din[17],
        din[18], din[19], din[20], din[21], din[22], din[23], flags);
    prep_weights<<<288, 256, 0, stream>>>(din[8], din[13], wt1, wt2, flags);

    for (int b = 0; b < BATCH; ++b) {
        hipMemsetAsync(canvas, 0, (size_t)NYg*NXg*64*2, stream);
        pfn_scatter<<<NPIL/4, 256, 0, stream>>>(
            din[0], coords, din[3], din[4], din[5], din[6], din[7], flags, b, canvas);
        conv1_mt<<<dim3(2, OHh, 1), 256, 0, stream>>>(
            canvas, wt1, din[9], din[10], din[11], din[12], flags, x1);
        conv2_mt<<<dim3(2, OHh, 2), 256, 0, stream>>>(
            x1, wt2, din[14], din[15], din[16], din[17], flags, x2);
        heads_kernel<<<(HWp + 255)/256, 256, 0, stream>>>(
            x2, din[18], din[19], din[20], din[21], din[22], din[23], flags, b, out);
    }
}

// Round 9
// 872.306 us; speedup vs baseline: 2.2327x; 1.1962x over previous
//
#include <hip/hip_runtime.h>

// ---------------- constants ----------------
#define BATCH 4
#define NPIL 12000
#define NPTS 32
#define NCH 9
#define NXg 432
#define NYg 496
#define OHh 248
#define OWw 216
#define HWp (OHh*OWw)          // 53568
#define CAN_STRIDE ((size_t)NYg*NXg*64)      // ushort elems
#define X1_STRIDE  ((size_t)OHh*OWw*64)      // float elems
#define X2_STRIDE  ((size_t)OHh*OWw*128)     // float elems

__device__ __forceinline__ float b2f(unsigned int u) {
    union { unsigned int i; float f; } x; x.i = (u & 0xffffu) << 16; return x.f;
}
__device__ __forceinline__ unsigned short f2b(float f) {
    union { float f; unsigned int i; } x; x.f = f;
    unsigned int r = x.i + 0x7fffu + ((x.i >> 16) & 1u);   // RNE
    return (unsigned short)(r >> 16);
}
__device__ __forceinline__ float ldin(const void* p, int i, int isbf) {
    return isbf ? b2f(((const unsigned short*)p)[i]) : ((const float*)p)[i];
}

__global__ void sentinel_kernel(float* out, float val) {
    if (threadIdx.x == 0) out[0] = val;
}

// ---------------- per-tensor dtype detector (robustness; all fp32 in practice) ----------------
__device__ __forceinline__ int plaus16(unsigned short h) {
    if ((h & 0x7fffu) == 0) return 1;
    unsigned e = (h >> 7) & 0xffu;
    return (e >= 106 && e <= 132) ? 1 : 0;
}

__global__ __launch_bounds__(1024) void detect_all(
    const void* q0,  const void* q1,  const void* q2,  const void* q3,
    const void* q4,  const void* q5,  const void* q6,  const void* q7,
    const void* q8,  const void* q9,  const void* q10, const void* q11,
    const void* q12, const void* q13, const void* q14, const void* q15,
    const void* q16, const void* q17, const void* q18, const void* q19,
    const void* q20, const void* q21, int* __restrict__ flags)
{
    __shared__ int votes[22];
    const void* ptrs[22] = {q0,q1,q2,q3,q4,q5,q6,q7,q8,q9,q10,q11,
                            q12,q13,q14,q15,q16,q17,q18,q19,q20,q21};
    const int Ks[22]   = {64,64,32,32,32,32,64,32,32,32,32,64,64,64,64,64,64,3,64,7,64,2};
    const int didx[22] = {0,3,4,5,6,7,8,9,10,11,12,13,14,15,16,17,18,19,20,21,22,23};
    const int tid = threadIdx.x;
    if (tid < 22) votes[tid] = 0;
    __syncthreads();
    int off = 0;
    #pragma unroll 1
    for (int t = 0; t < 22; ++t) {
        const int K = Ks[t];
        if (tid >= off && tid < off + K) {
            unsigned w = ((const unsigned*)ptrs[t])[tid - off];
            if (plaus16((unsigned short)w) && plaus16((unsigned short)(w >> 16)))
                atomicAdd(&votes[t], 1);
        }
        off += K;
    }
    __syncthreads();
    if (tid < 22) {
        int isbf;
        if (tid == 17 || tid == 19 || tid == 21) {
            int pv = votes[17] + votes[19] + votes[21];
            isbf = (pv * 4 >= 3 * 12);
        } else {
            isbf = (votes[tid] * 4 >= 3 * Ks[tid]);
        }
        flags[didx[tid]] = isbf;
    }
}

// ---------------- weight transpose: OIHW -> [ky*3+kx][ic][oc] fp32 ----------------
__global__ __launch_bounds__(256) void prep_weights(
    const void* __restrict__ w1, const void* __restrict__ w2,
    float* __restrict__ wt1, float* __restrict__ wt2,
    const int* __restrict__ flags)
{
    const int f1 = flags[8], f2 = flags[13];
    int i = blockIdx.x * 256 + threadIdx.x;
    if (i < 64*64*9) {
        int kx = i % 3; int t = i / 3; int ky = t % 3; t /= 3; int ic = t % 64; int oc = t / 64;
        wt1[((ky*3 + kx)*64 + ic)*64 + oc] = ldin(w1, i, f1);
    }
    if (i < 128*64*9) {
        int kx = i % 3; int t = i / 3; int ky = t % 3; t /= 3; int ic = t % 64; int oc = t / 64;
        wt2[((ky*3 + kx)*64 + ic)*128 + oc] = ldin(w2, i, f2);
    }
}

// ---------------- PFN + scatter, canvas NHWC bf16 [NY,NX,64] ----------------
// grid.y = nb batches; b0 = first batch index
__global__ __launch_bounds__(256) void pfn_scatter(
    const void* __restrict__ pillars, const int* __restrict__ coords,
    const void* __restrict__ pfn_w,
    const void* __restrict__ g, const void* __restrict__ bb,
    const void* __restrict__ m, const void* __restrict__ v,
    const int* __restrict__ flags, int b0,
    unsigned short* __restrict__ canvas)
{
    __shared__ float lds[4][NPTS*NCH];
    const int wslot = threadIdx.x >> 6;
    const int lane  = threadIdx.x & 63;
    const int p = blockIdx.x * 4 + wslot;
    const int b = b0 + blockIdx.y;
    canvas += (size_t)blockIdx.y * CAN_STRIDE;
    const size_t pg = (size_t)b * NPIL + p;

    if (flags[0]) {
        const unsigned short* src = (const unsigned short*)pillars + pg * (NPTS*NCH);
        for (int idx = lane; idx < NPTS*NCH; idx += 64) lds[wslot][idx] = b2f(src[idx]);
    } else {
        const float4* src = (const float4*)((const float*)pillars + pg * (NPTS*NCH));
        for (int idx = lane; idx < (NPTS*NCH)/4; idx += 64)
            *(float4*)&lds[wslot][idx*4] = src[idx];
    }
    float w[NCH];
    const int fW = flags[3];
    #pragma unroll
    for (int c = 0; c < NCH; ++c) w[c] = ldin(pfn_w, lane*NCH + c, fW);
    float s = ldin(g, lane, flags[4]) / sqrtf(ldin(v, lane, flags[7]) + 1e-5f);
    float t = ldin(bb, lane, flags[5]) - ldin(m, lane, flags[6]) * s;
    __syncthreads();

    float mx = 0.0f;
    #pragma unroll 4
    for (int n = 0; n < NPTS; ++n) {
        const float* r = &lds[wslot][n*NCH];
        float acc = r[0] * w[0];
        #pragma unroll
        for (int c = 1; c < NCH; ++c) acc = fmaf(r[c], w[c], acc);
        mx = fmaxf(mx, fmaxf(fmaf(acc, s, t), 0.0f));
    }
    const int cx = coords[pg*2], cy = coords[pg*2 + 1];
    if (cx + cy != 0 && cx >= 0 && cx < NXg && cy >= 0 && cy < NYg)
        canvas[((size_t)cy*NXg + cx)*64 + lane] = f2b(mx);
}

// XOR-swizzled LDS offset: element (px, icq 0..15) -> conflict-free pg-strided reads
#define SWZ(px, icq) ((px)*64 + (((icq) ^ ((px) & 15)) << 2))

// ---------------- conv1: canvas bf16 -> x1 fp32 [248,216,64], stride 2 ----------------
// 16 oc-threads x 4oc, 16 px-groups x 7px. lw staged in ic-halves. LDS 53,376 B -> 3 blk/CU.
__global__ __launch_bounds__(256, 3) void conv1_mt(
    const unsigned short* __restrict__ canvas,
    const float* __restrict__ wt,          // [ky*3+kx][ic][64]
    const void* __restrict__ g, const void* __restrict__ bb,
    const void* __restrict__ m, const void* __restrict__ v,
    const int* __restrict__ flags,
    float* __restrict__ out)
{
    __shared__ __align__(16) unsigned short lin[225*64];   // 28,800 B (swizzled)
    __shared__ __align__(16) float lw[3*32*64];            // 24,576 B
    const int tid = threadIdx.x;
    const int oc_t = tid & 15, pg = tid >> 4;
    const int oc0 = oc_t*4;
    const int bx = blockIdx.x, oy = blockIdx.y;
    canvas += (size_t)blockIdx.z * CAN_STRIDE;
    out    += (size_t)blockIdx.z * X1_STRIDE;
    const int gx0 = bx*224 - 1;

    float4 acc[7];
    #pragma unroll
    for (int i = 0; i < 7; ++i) acc[i] = make_float4(0.f,0.f,0.f,0.f);

    #pragma unroll 1
    for (int ky = 0; ky < 3; ++ky) {
        const int iy = 2*oy + ky - 1;
        __syncthreads();
        if (iy < 0 || iy >= NYg) continue;     // block-uniform
        {   // stage input row bf16 (swizzled, zero-padded)
            const unsigned short* row = canvas + (size_t)iy*NXg*64;
            for (int q = tid; q < 225*16; q += 256) {
                int px = q >> 4, icq = q & 15;
                int gx = gx0 + px;
                uint2 d = make_uint2(0u, 0u);
                if (gx >= 0 && gx < NXg) d = *(const uint2*)&row[(size_t)gx*64 + icq*4];
                *(uint2*)&lin[SWZ(px, icq)] = d;
            }
        }
        #pragma unroll 1
        for (int h = 0; h < 2; ++h) {
            if (h) __syncthreads();            // drain reads of previous lw half
            for (int j = tid; j < 3*32*16; j += 256) {   // stage lw ic-half
                int kx = j >> 9, r = j & 511, icl = r >> 4, qo = r & 15;
                *(float4*)&lw[(kx*32 + icl)*64 + qo*4] =
                    *(const float4*)&wt[(((size_t)(ky*3 + kx))*64 + h*32 + icl)*64 + qo*4];
            }
            __syncthreads();
            #pragma unroll 1
            for (int ig = 0; ig < 8; ++ig) {
                const int icg = h*8 + ig;
                float fq[15][4];
                #pragma unroll
                for (int j = 0; j < 15; ++j) {
                    const int px = 14*pg + j;
                    uint2 d = *(const uint2*)&lin[SWZ(px, icg)];
                    fq[j][0] = b2f(d.x); fq[j][1] = b2f(d.x >> 16);
                    fq[j][2] = b2f(d.y); fq[j][3] = b2f(d.y >> 16);
                }
                #pragma unroll
                for (int kx = 0; kx < 3; ++kx)
                #pragma unroll
                for (int ic = 0; ic < 4; ++ic) {
                    const float4 w4 = *(const float4*)&lw[(kx*32 + ig*4 + ic)*64 + oc0];
                    #pragma unroll
                    for (int i = 0; i < 7; ++i) {
                        const float a = fq[2*i + kx][ic];
                        acc[i].x = fmaf(a, w4.x, acc[i].x);
                        acc[i].y = fmaf(a, w4.y, acc[i].y);
                        acc[i].z = fmaf(a, w4.z, acc[i].z);
                        acc[i].w = fmaf(a, w4.w, acc[i].w);
                    }
                }
            }
        }
    }
    float s[4], t[4];
    #pragma unroll
    for (int c = 0; c < 4; ++c) {
        s[c] = ldin(g, oc0+c, flags[9]) / sqrtf(ldin(v, oc0+c, flags[12]) + 1e-5f);
        t[c] = ldin(bb, oc0+c, flags[10]) - ldin(m, oc0+c, flags[11]) * s[c];
    }
    #pragma unroll
    for (int i = 0; i < 7; ++i) {
        const int px = bx*112 + pg*7 + i;
        if (px < OWw) {
            float4 r;
            r.x = fmaxf(fmaf(acc[i].x, s[0], t[0]), 0.f);
            r.y = fmaxf(fmaf(acc[i].y, s[1], t[1]), 0.f);
            r.z = fmaxf(fmaf(acc[i].z, s[2], t[2]), 0.f);
            r.w = fmaxf(fmaf(acc[i].w, s[3], t[3]), 0.f);
            *(float4*)&out[((size_t)oy*OWw + px)*64 + oc0] = r;
        }
    }
}

// ---------------- conv2: x1 fp32 -> x2 fp32 [248,216,128], stride 1 ----------------
// grid.z = 2*nb: (batch, oc-half). LDS 53,760 B -> 3 blk/CU.
__global__ __launch_bounds__(256, 3) void conv2_mt(
    const float* __restrict__ x1,
    const float* __restrict__ wt,          // [ky*3+kx][ic][128]
    const void* __restrict__ g, const void* __restrict__ bb,
    const void* __restrict__ m, const void* __restrict__ v,
    const int* __restrict__ flags,
    float* __restrict__ out)
{
    __shared__ __align__(16) float lin[114*64];            // 29,184 B (swizzled)
    __shared__ __align__(16) float lw[3*32*64];            // 24,576 B
    const int tid = threadIdx.x;
    const int oc_t = tid & 15, pg = tid >> 4;
    const int zb = blockIdx.z >> 1, half = blockIdx.z & 1;
    const int oc = half*64 + oc_t*4;
    const int bx = blockIdx.x, oy = blockIdx.y;
    x1  += (size_t)zb * X1_STRIDE;
    out += (size_t)zb * X2_STRIDE;
    const int gx0 = bx*112 - 1;

    float4 acc[7];
    #pragma unroll
    for (int i = 0; i < 7; ++i) acc[i] = make_float4(0.f,0.f,0.f,0.f);

    #pragma unroll 1
    for (int ky = 0; ky < 3; ++ky) {
        const int iy = oy + ky - 1;
        __syncthreads();
        if (iy < 0 || iy >= OHh) continue;     // block-uniform
        {   // stage input row fp32 (swizzled, zero-padded)
            const float* row = x1 + (size_t)iy*OWw*64;
            for (int q = tid; q < 114*16; q += 256) {
                int px = q >> 4, icq = q & 15;
                int gx = gx0 + px;
                float4 d = make_float4(0.f,0.f,0.f,0.f);
                if (gx >= 0 && gx < OWw) d = *(const float4*)&row[(size_t)gx*64 + icq*4];
                *(float4*)&lin[SWZ(px, icq)] = d;
            }
        }
        #pragma unroll 1
        for (int h = 0; h < 2; ++h) {
            if (h) __syncthreads();
            for (int j = tid; j < 3*32*16; j += 256) {   // stage lw ic-half, oc-slice
                int kx = j >> 9, r = j & 511, icl = r >> 4, qo = r & 15;
                *(float4*)&lw[(kx*32 + icl)*64 + qo*4] =
                    *(const float4*)&wt[(((size_t)(ky*3 + kx))*64 + h*32 + icl)*128 + half*64 + qo*4];
            }
            __syncthreads();
            #pragma unroll 1
            for (int ig = 0; ig < 8; ++ig) {
                const int icg = h*8 + ig;
                float4 q[9];
                #pragma unroll
                for (int j = 0; j < 9; ++j) {
                    const int px = 7*pg + j;
                    q[j] = *(const float4*)&lin[SWZ(px, icg)];
                }
                #pragma unroll
                for (int kx = 0; kx < 3; ++kx)
                #pragma unroll
                for (int ic = 0; ic < 4; ++ic) {
                    const float4 w4 = *(const float4*)&lw[(kx*32 + ig*4 + ic)*64 + oc_t*4];
                    #pragma unroll
                    for (int i = 0; i < 7; ++i) {
                        const float a = ((const float*)&q[i + kx])[ic];
                        acc[i].x = fmaf(a, w4.x, acc[i].x);
                        acc[i].y = fmaf(a, w4.y, acc[i].y);
                        acc[i].z = fmaf(a, w4.z, acc[i].z);
                        acc[i].w = fmaf(a, w4.w, acc[i].w);
                    }
                }
            }
        }
    }
    float s[4], t[4];
    #pragma unroll
    for (int c = 0; c < 4; ++c) {
        s[c] = ldin(g, oc+c, flags[14]) / sqrtf(ldin(v, oc+c, flags[17]) + 1e-5f);
        t[c] = ldin(bb, oc+c, flags[15]) - ldin(m, oc+c, flags[16]) * s[c];
    }
    #pragma unroll
    for (int i = 0; i < 7; ++i) {
        const int px = bx*112 + pg*7 + i;
        if (px < OWw) {
            float4 r;
            r.x = fmaxf(fmaf(acc[i].x, s[0], t[0]), 0.f);
            r.y = fmaxf(fmaf(acc[i].y, s[1], t[1]), 0.f);
            r.z = fmaxf(fmaf(acc[i].z, s[2], t[2]), 0.f);
            r.w = fmaxf(fmaf(acc[i].w, s[3], t[3]), 0.f);
            *(float4*)&out[((size_t)oy*OWw + px)*128 + oc] = r;
        }
    }
}

// ---------------- detection heads (1x1 convs), fp32 out ----------------
__global__ __launch_bounds__(256) void heads_kernel(
    const float* __restrict__ x2,
    const void* __restrict__ cls_w, const void* __restrict__ cls_b,
    const void* __restrict__ reg_w, const void* __restrict__ reg_b,
    const void* __restrict__ dir_w, const void* __restrict__ dir_b,
    const int* __restrict__ flags, int nb, int b0,
    float* __restrict__ out)
{
    __shared__ float lw[24*128];
    __shared__ float lb[24];
    const int tid = threadIdx.x;
    for (int idx = tid; idx < 6*128;  idx += 256) lw[idx]          = ldin(cls_w, idx, flags[18]);
    for (int idx = tid; idx < 14*128; idx += 256) lw[6*128 + idx]  = ldin(reg_w, idx, flags[20]);
    for (int idx = tid; idx < 4*128;  idx += 256) lw[20*128 + idx] = ldin(dir_w, idx, flags[22]);
    if (tid < 6)       lb[tid] = ldin(cls_b, tid, flags[19]);
    else if (tid < 20) lb[tid] = ldin(reg_b, tid - 6, flags[21]);
    else if (tid < 24) lb[tid] = ldin(dir_b, tid - 20, flags[23]);
    __syncthreads();

    const int gpix = blockIdx.x * 256 + tid;
    int b, pix;
    const float* xrow;
    if (nb > 1) {
        if (gpix >= nb*HWp) return;
        b = gpix / HWp; pix = gpix - b*HWp;
        xrow = x2 + (size_t)b * X2_STRIDE + (size_t)pix * 128;
    } else {
        if (gpix >= HWp) return;
        b = b0; pix = gpix;
        xrow = x2 + (size_t)pix * 128;
    }

    float acc[24];
    #pragma unroll
    for (int o = 0; o < 24; ++o) acc[o] = lb[o];
    #pragma unroll 2
    for (int kb = 0; kb < 128; kb += 16) {
        float xv[16];
        #pragma unroll
        for (int j = 0; j < 4; ++j) {
            float4 v4 = *(const float4*)(xrow + kb + 4*j);
            xv[4*j] = v4.x; xv[4*j+1] = v4.y; xv[4*j+2] = v4.z; xv[4*j+3] = v4.w;
        }
        #pragma unroll
        for (int k = 0; k < 16; ++k)
            #pragma unroll
            for (int o = 0; o < 24; ++o)
                acc[o] = fmaf(xv[k], lw[o*128 + kb + k], acc[o]);
    }
    const size_t reg_base = (size_t)BATCH*6*HWp;
    const size_t dir_base = reg_base + (size_t)BATCH*14*HWp;
    #pragma unroll
    for (int o = 0; o < 6; ++o)
        out[((size_t)b*6 + o)*HWp + pix] = acc[o];
    #pragma unroll
    for (int o = 0; o < 14; ++o)
        out[reg_base + ((size_t)b*14 + o)*HWp + pix] = acc[6 + o];
    #pragma unroll
    for (int o = 0; o < 4; ++o)
        out[dir_base + ((size_t)b*4 + o)*HWp + pix] = acc[20 + o];
}

extern "C" void kernel_launch(void* const* d_in, const int* in_sizes, int n_in,
                              void* d_out, int out_size, void* d_ws, size_t ws_size,
                              hipStream_t stream) {
    static const int EXPECT[24] = {13824000,96000,48000,576,64,64,64,64,36864,
                                   64,64,64,64,73728,128,128,128,128,768,6,1792,14,512,4};
    const void* din[24];
    {
        bool used[24] = {false};
        int perm[24];
        bool ok = (n_in >= 24);
        if (ok) {
            for (int j = 0; j < 24 && ok; ++j) {
                perm[j] = -1;
                for (int i = 0; i < 24; ++i)
                    if (!used[i] && in_sizes[i] == EXPECT[j]) { perm[j] = i; used[i] = true; break; }
                if (perm[j] < 0) ok = false;
            }
        }
        for (int j = 0; j < 24; ++j) din[j] = d_in[ok ? perm[j] : j];
        if (!ok) {
            sentinel_kernel<<<1, 64, 0, stream>>>((float*)d_out, 13000.0f + n_in);
            return;
        }
    }
    const int* coords = (const int*)din[1];
    float* out = (float*)d_out;

    // layout: flags 256B | wt1 147KB | wt2 295KB | x1 (nb x 13.71MB) | canvas (nb x 27.43MB, x2 aliases)
    const size_t X1B = 13713408, CANB = 27426816;
    const size_t NEED1 = 442624 + X1B + CANB;            // 41,582,848
    const size_t NEED4 = 442624 + 4*X1B + 4*CANB;        // 165,003,520
    if (ws_size < NEED1) {
        sentinel_kernel<<<1, 64, 0, stream>>>(out, 10000.0f + (float)(ws_size >> 20));
        return;
    }
    const int nb = (ws_size >= NEED4) ? 4 : 1;
    char* ws = (char*)d_ws;
    int*   flags = (int*)ws;
    float* wt1   = (float*)(ws + 256);
    float* wt2   = (float*)(ws + 147712);
    float* x1    = (float*)(ws + 442624);
    unsigned short* canvas = (unsigned short*)(ws + 442624 + (size_t)nb*X1B);
    float* x2    = (float*)canvas;                       // aliases canvas (dead after conv1)

    detect_all<<<1, 1024, 0, stream>>>(
        din[0], din[3], din[4], din[5], din[6], din[7],
        din[8], din[9], din[10], din[11], din[12],
        din[13], din[14], din[15], din[16], din[17],
        din[18], din[19], din[20], din[21], din[22], din[23], flags);
    prep_weights<<<288, 256, 0, stream>>>(din[8], din[13], wt1, wt2, flags);

    if (nb == 4) {
        hipMemsetAsync(canvas, 0, 4*CANB, stream);
        pfn_scatter<<<dim3(NPIL/4, 4), 256, 0, stream>>>(
            din[0], coords, din[3], din[4], din[5], din[6], din[7], flags, 0, canvas);
        conv1_mt<<<dim3(2, OHh, 4), 256, 0, stream>>>(
            canvas, wt1, din[9], din[10], din[11], din[12], flags, x1);
        conv2_mt<<<dim3(2, OHh, 8), 256, 0, stream>>>(
            x1, wt2, din[14], din[15], din[16], din[17], flags, x2);
        heads_kernel<<<(4*HWp)/256, 256, 0, stream>>>(
            x2, din[18], din[19], din[20], din[21], din[22], din[23], flags, 4, 0, out);
    } else {
        for (int b = 0; b < BATCH; ++b) {
            hipMemsetAsync(canvas, 0, CANB, stream);
            pfn_scatter<<<dim3(NPIL/4, 1), 256, 0, stream>>>(
                din[0], coords, din[3], din[4], din[5], din[6], din[7], flags, b, canvas);
            conv1_mt<<<dim3(2, OHh, 1), 256, 0, stream>>>(
                canvas, wt1, din[9], din[10], din[11], din[12], flags, x1);
            conv2_mt<<<dim3(2, OHh, 2), 256, 0, stream>>>(
                x1, wt2, din[14], din[15], din[16], din[17], flags, x2);
            heads_kernel<<<(HWp + 255)/256, 256, 0, stream>>>(
                x2, din[18], din[19], din[20], din[21], din[22], din[23], flags, 1, b, out);
        }
    }
}